// Round 10
// baseline (717.679 us; speedup 1.0000x reference)
//
#include <hip/hip_runtime.h>
#include <hip/hip_fp16.h>

#define D 128
#define SCH 4096    // elements per scan block
#define NBLK 256    // blocks per level-1 distribution

// ---------------- task structs (passed by value) -----------------------------
struct HTask { const int* keys; int n; int shift; int* H; };
struct H6 { HTask t[6]; };

struct SPTask { const int* in; int n; int* part; };
struct SP6 { SPTask t[6]; };

struct SDTask { const int* in; int n; const int* part; int* out; int* total; };
struct SD6 { SDTask t[6]; };

struct ScTask { const int* k1; const int* k2; int n; int shift;
                const int* base1; const int* base2;
                int* o1; int* o2k; int* o2v; int mode; };
struct Sc4 { ScTask t[4]; };

struct CTask { const int* tmpk; const int* base; int n; int fine; int* deg; };
struct C4 { CTask t[4]; };

struct NTask { const int* outdeg; const int* indeg; float* ns; float* nd; int n; };
struct N2 { NTask t[2]; };

struct LTask { const int* tmpk; const int* tmpv; const int* base; int n;
               const int* rowptr; int shift; int fine; int* col; };
struct L2T { LTask t[2]; };

struct GTask { const float* x; const float* ns; const float* W; __half* h; int K; };
struct GemP { GTask t[2]; int nb0; };

struct ATask { const __half* h; const int* rowptr; const int* col;
               const float* nd; const float* b; void* out; int halfOut; };
struct AggP { ATask t[2]; int np; int ntot; };

struct MTask { const __half* x; const int* gbase; int n; const int* list; float* out; };
struct M2 { MTask t[2]; };

// ---------------- fused preprocessing ----------------------------------------

__global__ __launch_bounds__(256) void k_hist_all(H6 P) {
  HTask tk = P.t[blockIdx.y];
  __shared__ int bins[256];
  int blk = blockIdx.x, t = threadIdx.x;
  bins[t] = 0;
  __syncthreads();
  int per = (tk.n + NBLK - 1) / NBLK;
  int beg = blk * per, end = min(beg + per, tk.n);
  for (int i = beg + t; i < end; i += 256)
    atomicAdd(&bins[tk.keys[i] >> tk.shift], 1);
  __syncthreads();
  tk.H[t * NBLK + blk] = bins[t];
}

__global__ __launch_bounds__(256) void k_scan_part_all(SP6 P) {
  SPTask tk = P.t[blockIdx.y];
  int b = blockIdx.x, t = threadIdx.x;
  int base = b * SCH;
  int s = 0;
  for (int i = t; i < SCH; i += 256) {
    int idx = base + i;
    if (idx < tk.n) s += tk.in[idx];
  }
  __shared__ int red[256];
  red[t] = s;
  __syncthreads();
  for (int d = 128; d > 0; d >>= 1) {
    if (t < d) red[t] += red[t + d];
    __syncthreads();
  }
  if (t == 0) tk.part[b] = red[0];
}

__global__ __launch_bounds__(256) void k_scan_down_all(SD6 P) {
  SDTask tk = P.t[blockIdx.y];
  int b = blockIdx.x, t = threadIdx.x;
  int lane = t & 63, wid = t >> 6;
  __shared__ int wsum[4];
  if (b == 0 && t == 0 && tk.total) {
    int s = 0;
    for (int w = 0; w < (int)gridDim.x; ++w) s += tk.part[w];
    *tk.total = s;
  }
  int offset = 0;
  for (int w = 0; w < b; ++w) offset += tk.part[w];
  int base = b * SCH;
  if (base >= tk.n) return;
  int idx0 = base + t * 16;
  int v[16];
  int s = 0;
#pragma unroll
  for (int i = 0; i < 16; ++i) {
    int idx = idx0 + i;
    v[i] = (idx < tk.n) ? tk.in[idx] : 0;
    s += v[i];
  }
  int inc = s;
  for (int d = 1; d < 64; d <<= 1) {
    int u = __shfl_up(inc, d, 64);
    if (lane >= d) inc += u;
  }
  if (lane == 63) wsum[wid] = inc;
  __syncthreads();
  int woff = 0;
  for (int w = 0; w < wid; ++w) woff += wsum[w];
  int ex = offset + woff + inc - s;
#pragma unroll
  for (int i = 0; i < 16; ++i) {
    int idx = idx0 + i;
    if (idx < tk.n) tk.out[idx] = ex;
    ex += v[i];
  }
}

__global__ __launch_bounds__(256) void k_scatter_all(Sc4 P) {
  ScTask tk = P.t[blockIdx.y];
  __shared__ int curA[256], curB[256];
  int blk = blockIdx.x, t = threadIdx.x;
  curA[t] = tk.base1[t * NBLK + blk];
  if (tk.mode == 0) curB[t] = tk.base2[t * NBLK + blk];
  __syncthreads();
  int per = (tk.n + NBLK - 1) / NBLK;
  int beg = blk * per, end = min(beg + per, tk.n);
  if (tk.mode == 0) {
    for (int i = beg + t; i < end; i += 256) {
      int s = tk.k1[i], d = tk.k2[i];
      int pa = atomicAdd(&curA[s >> tk.shift], 1);
      tk.o1[pa] = s;
      int pb = atomicAdd(&curB[d >> tk.shift], 1);
      tk.o2k[pb] = d;
      tk.o2v[pb] = s;
    }
  } else {
    for (int i = beg + t; i < end; i += 256) {
      int pa = atomicAdd(&curA[tk.k1[i] >> tk.shift], 1);
      tk.o1[pa] = i;
    }
  }
}

__global__ __launch_bounds__(256) void k_l2count_all(C4 P) {
  CTask tk = P.t[blockIdx.y];
  __shared__ int bins[512];
  int b = blockIdx.x, t = threadIdx.x;
  for (int f = t; f < tk.fine; f += 256) bins[f] = 0;
  __syncthreads();
  int beg = tk.base[b * NBLK];
  int end = (b == NBLK - 1) ? tk.n : tk.base[(b + 1) * NBLK];
  for (int i = beg + t; i < end; i += 256)
    atomicAdd(&bins[tk.tmpk[i] & (tk.fine - 1)], 1);
  __syncthreads();
  for (int f = t; f < tk.fine; f += 256)
    tk.deg[b * tk.fine + f] = bins[f];
}

__global__ __launch_bounds__(256) void k_norms_all(N2 P) {
  NTask tk = P.t[blockIdx.y];
  int i = blockIdx.x * blockDim.x + threadIdx.x;
  if (i < tk.n) {
    tk.ns[i] = rsqrtf(fmaxf((float)tk.outdeg[i], 1.f));
    tk.nd[i] = rsqrtf(fmaxf((float)tk.indeg[i], 1.f));
  }
}

__global__ __launch_bounds__(256) void k_l2scatter_all(L2T P) {
  LTask tk = P.t[blockIdx.y];
  __shared__ int cur[512];
  int b = blockIdx.x, t = threadIdx.x;
  int v0 = b << tk.shift;
  for (int f = t; f < tk.fine; f += 256) cur[f] = tk.rowptr[v0 + f];
  __syncthreads();
  int beg = tk.base[b * NBLK];
  int end = (b == NBLK - 1) ? tk.n : tk.base[(b + 1) * NBLK];
  for (int i = beg + t; i < end; i += 256) {
    int pos = atomicAdd(&cur[tk.tmpk[i] & (tk.fine - 1)], 1);
    tk.col[pos] = tk.tmpv[i];
  }
}

// ---------------- towers ------------------------------------------------------

// h[v,:] = fp16( ns[v] * (x[v,:] @ W) ); 32 nodes x 128 feats per block.
// W staged in LDS as fp32 in 64-row K-chunks -> K-loop is pure LDS+FMA.
// Numerics identical to the R8 kernel (fp32 inputs, fp32 FMA, fp16 output).
__global__ __launch_bounds__(256) void k_nl_gemm(GemP P) {
  __shared__ float xs[32][132];     // 16.9 KB
  __shared__ float wl[64][128];     // 32 KB -> total 49.7 KB, 3 blocks/CU
  int bx = blockIdx.x;
  GTask tk;
  int v0;
  if (bx < P.nb0) { tk = P.t[0]; v0 = bx * 32; }
  else            { tk = P.t[1]; v0 = (bx - P.nb0) * 32; }
  const int K = tk.K;
  int t = threadIdx.x;

  // stage x tile (coalesced)
  {
    int m = t >> 5, k = t & 31;
    for (int kk = k; kk < K; kk += 32)
      for (int mm = m; mm < 32; mm += 8)
        xs[mm][kk] = tk.x[(size_t)(v0 + mm) * K + kk];
  }

  int tm = (t >> 5) * 4;
  int tf = (t & 31) * 4;

  float acc[4][4];
#pragma unroll
  for (int i = 0; i < 4; ++i)
#pragma unroll
    for (int j = 0; j < 4; ++j) acc[i][j] = 0.f;

  for (int kbeg = 0; kbeg < K; kbeg += 64) {
    int rows = min(64, K - kbeg);
    __syncthreads();
    // stage W chunk: rows*128 floats, 16B per thread-iteration
    for (int idx = t; idx < rows * 32; idx += 256) {
      int r = idx >> 5, c4 = (idx & 31) * 4;
      *(float4*)&wl[r][c4] = *(const float4*)&tk.W[(size_t)(kbeg + r) * D + c4];
    }
    __syncthreads();

    int r4 = rows & ~3;
    for (int kk = 0; kk < r4; kk += 4) {
      float bb[4][4];
#pragma unroll
      for (int q = 0; q < 4; ++q) {
        float4 w4 = *(const float4*)&wl[kk + q][tf];
        bb[q][0] = w4.x; bb[q][1] = w4.y; bb[q][2] = w4.z; bb[q][3] = w4.w;
      }
#pragma unroll
      for (int i = 0; i < 4; ++i) {
        float4 a4 = *(const float4*)&xs[tm + i][kbeg + kk];
#pragma unroll
        for (int j = 0; j < 4; ++j) acc[i][j] = fmaf(a4.x, bb[0][j], acc[i][j]);
#pragma unroll
        for (int j = 0; j < 4; ++j) acc[i][j] = fmaf(a4.y, bb[1][j], acc[i][j]);
#pragma unroll
        for (int j = 0; j < 4; ++j) acc[i][j] = fmaf(a4.z, bb[2][j], acc[i][j]);
#pragma unroll
        for (int j = 0; j < 4; ++j) acc[i][j] = fmaf(a4.w, bb[3][j], acc[i][j]);
      }
    }
    for (int kk = r4; kk < rows; ++kk) {
      float4 w4 = *(const float4*)&wl[kk][tf];
      float bv[4] = {w4.x, w4.y, w4.z, w4.w};
#pragma unroll
      for (int i = 0; i < 4; ++i) {
        float av = xs[tm + i][kbeg + kk];
#pragma unroll
        for (int j = 0; j < 4; ++j) acc[i][j] = fmaf(av, bv[j], acc[i][j]);
      }
    }
  }

#pragma unroll
  for (int i = 0; i < 4; ++i) {
    int v = v0 + tm + i;
    float s = tk.ns[v];
    __half2 p0, p1;
    p0.x = __float2half_rn(acc[i][0] * s); p0.y = __float2half_rn(acc[i][1] * s);
    p1.x = __float2half_rn(acc[i][2] * s); p1.y = __float2half_rn(acc[i][3] * s);
    uint2 u;
    u.x = __builtin_bit_cast(unsigned, p0);
    u.y = __builtin_bit_cast(unsigned, p1);
    *(uint2*)&tk.h[(size_t)v * D + tf] = u;
  }
}

// ---- aggregation: wave-per-node, 16 lanes x 8 feats (16B), 4 rows/instr -----
__global__ __launch_bounds__(256) void k_aggregate(AggP P) {
  int wid = threadIdx.x >> 6;
  int lane = threadIdx.x & 63;
  int gv = blockIdx.x * 4 + wid;
  if (gv >= P.ntot) return;
  ATask tk;
  int v;
  if (gv < P.np) { tk = P.t[0]; v = gv; }
  else           { tk = P.t[1]; v = gv - P.np; }
  int beg = tk.rowptr[v], end = tk.rowptr[v + 1];
  int f0 = (lane & 15) * 8;
  int rsel = lane >> 4;
  const __half* h = tk.h;
  const int* col = tk.col;

  float acc[8];
#pragma unroll
  for (int k = 0; k < 8; ++k) acc[k] = 0.f;

  for (int j = beg; j < end; j += 8) {
    int j0 = j + rsel, j1 = j + 4 + rsel;
    if (j0 < end) {
      int c0 = col[j0];
      uint4 r = *(const uint4*)&h[(size_t)c0 * D + f0];
      const __half2* q = (const __half2*)&r;
#pragma unroll
      for (int k = 0; k < 4; ++k) {
        float2 f = __half22float2(q[k]);
        acc[2 * k] += f.x; acc[2 * k + 1] += f.y;
      }
    }
    if (j1 < end) {
      int c1 = col[j1];
      uint4 r = *(const uint4*)&h[(size_t)c1 * D + f0];
      const __half2* q = (const __half2*)&r;
#pragma unroll
      for (int k = 0; k < 4; ++k) {
        float2 f = __half22float2(q[k]);
        acc[2 * k] += f.x; acc[2 * k + 1] += f.y;
      }
    }
  }

#pragma unroll
  for (int k = 0; k < 8; ++k) {
    acc[k] += __shfl_down(acc[k], 32, 64);
    acc[k] += __shfl_down(acc[k], 16, 64);
  }

  if (rsel == 0) {
    float s = tk.nd[v];
    float4 b0 = *(const float4*)&tk.b[f0];
    float4 b1 = *(const float4*)&tk.b[f0 + 4];
    float r[8];
    r[0] = fmaxf(fmaf(acc[0], s, b0.x), 0.f);
    r[1] = fmaxf(fmaf(acc[1], s, b0.y), 0.f);
    r[2] = fmaxf(fmaf(acc[2], s, b0.z), 0.f);
    r[3] = fmaxf(fmaf(acc[3], s, b0.w), 0.f);
    r[4] = fmaxf(fmaf(acc[4], s, b1.x), 0.f);
    r[5] = fmaxf(fmaf(acc[5], s, b1.y), 0.f);
    r[6] = fmaxf(fmaf(acc[6], s, b1.z), 0.f);
    r[7] = fmaxf(fmaf(acc[7], s, b1.w), 0.f);
    if (tk.halfOut) {
      union { __half2 h2[4]; uint4 u; } pk;
#pragma unroll
      for (int k = 0; k < 4; ++k) {
        pk.h2[k].x = __float2half_rn(r[2 * k]);
        pk.h2[k].y = __float2half_rn(r[2 * k + 1]);
      }
      *(uint4*)&((__half*)tk.out)[(size_t)v * D + f0] = pk.u;
    } else {
      float4 o0 = {r[0], r[1], r[2], r[3]};
      float4 o1 = {r[4], r[5], r[6], r[7]};
      *(float4*)&((float*)tk.out)[(size_t)v * D + f0] = o0;
      *(float4*)&((float*)tk.out)[(size_t)v * D + f0 + 4] = o1;
    }
  }
}

__device__ __forceinline__ void acc_half4(float4& a, const __half* p) {
  uint2 r = *(const uint2*)p;
  __half2 q0 = *(__half2*)&r.x;
  __half2 q1 = *(__half2*)&r.y;
  float2 f0 = __half22float2(q0);
  float2 f1 = __half22float2(q1);
  a.x += f0.x; a.y += f0.y; a.z += f1.x; a.w += f1.y;
}

__global__ __launch_bounds__(256) void k_seg_mean(M2 P) {
  MTask tk = P.t[blockIdx.y];
  int g = blockIdx.x, t = threadIdx.x;
  int slot = t >> 5;
  int c = (t & 31) * 4;
  int beg = tk.gbase[g * NBLK];
  int end = (g == (int)gridDim.x - 1) ? tk.n : tk.gbase[(g + 1) * NBLK];
  const __half* x = tk.x;
  const int* list = tk.list;

  float4 a0 = make_float4(0.f, 0.f, 0.f, 0.f);
  float4 a1 = make_float4(0.f, 0.f, 0.f, 0.f);
  int j = beg + slot;
  for (; j + 8 < end; j += 16) {
    int s0 = list[j], s1 = list[j + 8];
    acc_half4(a0, x + (size_t)s0 * D + c);
    acc_half4(a1, x + (size_t)s1 * D + c);
  }
  if (j < end)
    acc_half4(a0, x + (size_t)list[j] * D + c);
  a0.x += a1.x; a0.y += a1.y; a0.z += a1.z; a0.w += a1.w;

  a0.x += __shfl_down(a0.x, 32, 64);
  a0.y += __shfl_down(a0.y, 32, 64);
  a0.z += __shfl_down(a0.z, 32, 64);
  a0.w += __shfl_down(a0.w, 32, 64);

  __shared__ float sred[4][32 * 4];
  int wid = t >> 6, lane = t & 63;
  if (lane < 32) *(float4*)&sred[wid][lane * 4] = a0;
  __syncthreads();
  if (t < 32) {
    float4 s0 = *(const float4*)&sred[0][t * 4];
    float4 s1 = *(const float4*)&sred[1][t * 4];
    float4 s2 = *(const float4*)&sred[2][t * 4];
    float4 s3 = *(const float4*)&sred[3][t * 4];
    float inv = 1.f / fmaxf((float)(end - beg), 1.f);
    float4 r;
    r.x = (s0.x + s1.x + s2.x + s3.x) * inv;
    r.y = (s0.y + s1.y + s2.y + s3.y) * inv;
    r.z = (s0.z + s1.z + s2.z + s3.z) * inv;
    r.w = (s0.w + s1.w + s2.w + s3.w) * inv;
    *(float4*)&tk.out[(size_t)g * D + c] = r;
  }
}

__global__ void k_mlp(const float* __restrict__ cg, const float* __restrict__ pg,
                      const float* __restrict__ Wf1, const float* __restrict__ bf1,
                      const float* __restrict__ Wf2, const float* __restrict__ bf2,
                      float* __restrict__ out) {
  __shared__ float xs[256];
  __shared__ float red[128];
  int b = blockIdx.x, t = threadIdx.x;
  xs[t] = cg[b * D + t];
  xs[128 + t] = pg[b * D + t];
  __syncthreads();
  float acc = bf1[t];
  for (int k = 0; k < 256; ++k) acc = fmaf(xs[k], Wf1[k * D + t], acc);
  float hv = fmaxf(acc, 0.f);
  red[t] = hv * Wf2[t];
  for (int d = 64; d > 0; d >>= 1) {
    __syncthreads();
    if (t < d) red[t] += red[t + d];
  }
  if (t == 0) out[b] = red[0] + bf2[0];
}

// ---------------- launch ------------------------------------------------------

extern "C" void kernel_launch(void* const* d_in, const int* in_sizes, int n_in,
                              void* d_out, int out_size, void* d_ws, size_t ws_size,
                              hipStream_t stream) {
  const float* compound_feat = (const float*)d_in[0];
  const float* protein_feat  = (const float*)d_in[1];
  const int* c_src = (const int*)d_in[2];
  const int* c_dst = (const int*)d_in[3];
  const int* p_src = (const int*)d_in[4];
  const int* p_dst = (const int*)d_in[5];
  const int* c_gid = (const int*)d_in[6];
  const int* p_gid = (const int*)d_in[7];
  const float* Wc1 = (const float*)d_in[8];  const float* bc1 = (const float*)d_in[9];
  const float* Wc2 = (const float*)d_in[10]; const float* bc2 = (const float*)d_in[11];
  const float* Wp1 = (const float*)d_in[12]; const float* bp1 = (const float*)d_in[13];
  const float* Wp2 = (const float*)d_in[14]; const float* bp2 = (const float*)d_in[15];
  const float* Wf1 = (const float*)d_in[16]; const float* bf1 = (const float*)d_in[17];
  const float* Wf2 = (const float*)d_in[18]; const float* bf2 = (const float*)d_in[19];
  float* out = (float*)d_out;

  const int EC = in_sizes[2], EP = in_sizes[4];
  const int NC = in_sizes[6], NP = in_sizes[7];
  const int B  = out_size;
  const int KC = in_sizes[0] / NC;                 // 74
  const int cshift = __builtin_ctz(NC / 256), cfine = NC / 256;
  const int pshift = __builtin_ctz(NP / 256), pfine = NP / 256;
  const int HN = 256 * NBLK;

  char* ws = (char*)d_ws;
  size_t off = 0;
  auto alloc = [&](size_t bytes) -> void* {
    void* p = ws + off;
    off += (bytes + 255) & ~(size_t)255;
    return p;
  };

  int* H0 = (int*)alloc((size_t)HN * 4);
  int* H1 = (int*)alloc((size_t)HN * 4);
  int* H2 = (int*)alloc((size_t)HN * 4);
  int* H3 = (int*)alloc((size_t)HN * 4);
  int* H4 = (int*)alloc((size_t)HN * 4);
  int* H5 = (int*)alloc((size_t)HN * 4);
  int* partH = (int*)alloc((size_t)6 * 32 * 4);
  int* partD = (int*)alloc((size_t)2 * 32 * 4);
  int* tmps_c = (int*)alloc((size_t)EC * 4);
  int* tmpd_c = (int*)alloc((size_t)EC * 4);
  int* tmpv_c = (int*)alloc((size_t)EC * 4);
  int* tmps_p = (int*)alloc((size_t)EP * 4);
  int* tmpd_p = (int*)alloc((size_t)EP * 4);
  int* tmpv_p = (int*)alloc((size_t)EP * 4);
  int* c_outdeg = (int*)alloc((size_t)NC * 4);
  int* c_indeg  = (int*)alloc((size_t)NC * 4);
  int* p_outdeg = (int*)alloc((size_t)NP * 4);
  int* p_indeg  = (int*)alloc((size_t)NP * 4);
  float* c_ns = (float*)alloc((size_t)NC * 4);
  float* c_nd = (float*)alloc((size_t)NC * 4);
  float* p_ns = (float*)alloc((size_t)NP * 4);
  float* p_nd = (float*)alloc((size_t)NP * 4);
  int* c_rowptr = (int*)alloc((size_t)(NC + 1) * 4);
  int* p_rowptr = (int*)alloc((size_t)(NP + 1) * 4);
  int* c_col   = (int*)alloc((size_t)EC * 4);
  int* p_col   = (int*)alloc((size_t)EP * 4);
  int* cg_list = (int*)alloc((size_t)NC * 4);
  int* pg_list = (int*)alloc((size_t)NP * 4);
  __half* c_h  = (__half*)alloc((size_t)NC * D * 2);
  float*  c_m1 = (float*) alloc((size_t)NC * D * 4);
  __half* c_m2 = (__half*)alloc((size_t)NC * D * 2);
  __half* p_h  = (__half*)alloc((size_t)NP * D * 2);
  float*  p_m1 = (float*) alloc((size_t)NP * D * 4);
  __half* p_m2 = (__half*)alloc((size_t)NP * D * 2);
  float* cg = (float*)alloc((size_t)B * D * 4);
  float* pg = (float*)alloc((size_t)B * D * 4);
  (void)ws_size; (void)n_in;

  // 1) all six 256-bin histograms
  {
    H6 P = {{{c_src, EC, cshift, H0}, {c_dst, EC, cshift, H1}, {c_gid, NC, 0, H2},
             {p_src, EP, pshift, H3}, {p_dst, EP, pshift, H4}, {p_gid, NP, 0, H5}}};
    k_hist_all<<<dim3(NBLK, 6), 256, 0, stream>>>(P);
  }
  // 2) scan the six H arrays in place
  {
    SP6 Pp = {{{H0, HN, partH + 0}, {H1, HN, partH + 32}, {H2, HN, partH + 64},
               {H3, HN, partH + 96}, {H4, HN, partH + 128}, {H5, HN, partH + 160}}};
    k_scan_part_all<<<dim3(16, 6), 256, 0, stream>>>(Pp);
    SD6 Pd = {{{H0, HN, partH + 0, H0, nullptr}, {H1, HN, partH + 32, H1, nullptr},
               {H2, HN, partH + 64, H2, nullptr}, {H3, HN, partH + 96, H3, nullptr},
               {H4, HN, partH + 128, H4, nullptr}, {H5, HN, partH + 160, H5, nullptr}}};
    k_scan_down_all<<<dim3(16, 6), 256, 0, stream>>>(Pd);
  }
  // 3) all level-1 scatters
  {
    Sc4 P = {{{c_src, c_dst, EC, cshift, H0, H1, tmps_c, tmpd_c, tmpv_c, 0},
              {p_src, p_dst, EP, pshift, H3, H4, tmps_p, tmpd_p, tmpv_p, 0},
              {c_gid, nullptr, NC, 0, H2, nullptr, cg_list, nullptr, nullptr, 1},
              {p_gid, nullptr, NP, 0, H5, nullptr, pg_list, nullptr, nullptr, 1}}};
    k_scatter_all<<<dim3(NBLK, 4), 256, 0, stream>>>(P);
  }
  // 4) level-2 counts -> degrees
  {
    C4 P = {{{tmps_c, H0, EC, cfine, c_outdeg}, {tmpd_c, H1, EC, cfine, c_indeg},
             {tmps_p, H3, EP, pfine, p_outdeg}, {tmpd_p, H4, EP, pfine, p_indeg}}};
    k_l2count_all<<<dim3(NBLK, 4), 256, 0, stream>>>(P);
  }
  // 5) scan indegrees -> rowptr
  {
    SP6 Pp; Pp.t[0] = {c_indeg, NC, partD + 0}; Pp.t[1] = {p_indeg, NP, partD + 32};
    Pp.t[2] = Pp.t[3] = Pp.t[4] = Pp.t[5] = SPTask{c_indeg, 0, partD + 0};
    k_scan_part_all<<<dim3(32, 2), 256, 0, stream>>>(Pp);
    SD6 Pd; Pd.t[0] = {c_indeg, NC, partD + 0, c_rowptr, c_rowptr + NC};
    Pd.t[1] = {p_indeg, NP, partD + 32, p_rowptr, p_rowptr + NP};
    Pd.t[2] = Pd.t[3] = Pd.t[4] = Pd.t[5] = Pd.t[0];
    k_scan_down_all<<<dim3(32, 2), 256, 0, stream>>>(Pd);
  }
  // 6) norms
  {
    N2 P = {{{c_outdeg, c_indeg, c_ns, c_nd, NC}, {p_outdeg, p_indeg, p_ns, p_nd, NP}}};
    k_norms_all<<<dim3((NP + 255) / 256, 2), 256, 0, stream>>>(P);
  }
  // 7) level-2 scatter -> CSR col
  {
    L2T P = {{{tmpd_c, tmpv_c, H1, EC, c_rowptr, cshift, cfine, c_col},
              {tmpd_p, tmpv_p, H4, EP, p_rowptr, pshift, pfine, p_col}}};
    k_l2scatter_all<<<dim3(NBLK, 2), 256, 0, stream>>>(P);
  }

  // ---- towers (flattened grids: protein first) ----
  const int gnb = NP / 32 + NC / 32;
  const int anb = (NP + NC + 3) / 4;
  {
    GemP P = {{{protein_feat, p_ns, Wp1, p_h, D}, {compound_feat, c_ns, Wc1, c_h, KC}}, NP / 32};
    k_nl_gemm<<<gnb, 256, 0, stream>>>(P);
  }
  {
    AggP P = {{{p_h, p_rowptr, p_col, p_nd, bp1, p_m1, 0},
               {c_h, c_rowptr, c_col, c_nd, bc1, c_m1, 0}}, NP, NP + NC};
    k_aggregate<<<anb, 256, 0, stream>>>(P);
  }
  {
    GemP P = {{{p_m1, p_ns, Wp2, p_h, D}, {c_m1, c_ns, Wc2, c_h, D}}, NP / 32};
    k_nl_gemm<<<gnb, 256, 0, stream>>>(P);
  }
  {
    AggP P = {{{p_h, p_rowptr, p_col, p_nd, bp2, p_m2, 1},
               {c_h, c_rowptr, c_col, c_nd, bc2, c_m2, 1}}, NP, NP + NC};
    k_aggregate<<<anb, 256, 0, stream>>>(P);
  }
  {
    M2 P = {{{c_m2, H2, NC, cg_list, cg}, {p_m2, H5, NP, pg_list, pg}}};
    k_seg_mean<<<dim3(B, 2), 256, 0, stream>>>(P);
  }

  k_mlp<<<B, D, 0, stream>>>(cg, pg, Wf1, bf1, Wf2, bf2, out);
}

// Round 11
// 671.937 us; speedup vs baseline: 1.0681x; 1.0681x over previous
//
#include <hip/hip_runtime.h>
#include <hip/hip_fp16.h>

#define D 128
#define SCH 4096    // elements per scan block
#define NBLK 256    // blocks per level-1 distribution

// ---------------- task structs (passed by value) -----------------------------
struct HTask { const int* keys; int n; int shift; int* H; };
struct H6 { HTask t[6]; };

struct SPTask { const int* in; int n; int* part; };
struct SP6 { SPTask t[6]; };

struct SDTask { const int* in; int n; const int* part; int* out; int* total; };
struct SD6 { SDTask t[6]; };

struct ScTask { const int* k1; const int* k2; int n; int shift;
                const int* base1; const int* base2;
                int* o1; int* o2k; int* o2v; int mode; };
struct Sc4 { ScTask t[4]; };

struct CTask { const int* tmpk; const int* base; int n; int fine; int* deg; };
struct C4 { CTask t[4]; };

struct NTask { const int* outdeg; const int* indeg; float* ns; float* nd; int n; };
struct N2 { NTask t[2]; };

struct LTask { const int* tmpk; const int* tmpv; const int* base; int n;
               const int* rowptr; int shift; int fine; int* col; };
struct L2T { LTask t[2]; };

struct GTask { const float* x; const float* ns; const float* W; __half* h; int K; };
struct GemP { GTask t[2]; int nb0; };

struct ATask { const __half* h; const int* rowptr; const int* col;
               const float* nd; const float* b; void* out; int halfOut; };
struct AggP { ATask t[2]; int np; int ntot; };

struct MTask { const __half* x; const int* gbase; int n; const int* list; float* out; };
struct M2 { MTask t[2]; };

// ---------------- fused preprocessing ----------------------------------------

__global__ __launch_bounds__(256) void k_hist_all(H6 P) {
  HTask tk = P.t[blockIdx.y];
  __shared__ int bins[256];
  int blk = blockIdx.x, t = threadIdx.x;
  bins[t] = 0;
  __syncthreads();
  int per = (tk.n + NBLK - 1) / NBLK;
  int beg = blk * per, end = min(beg + per, tk.n);
  for (int i = beg + t; i < end; i += 256)
    atomicAdd(&bins[tk.keys[i] >> tk.shift], 1);
  __syncthreads();
  tk.H[t * NBLK + blk] = bins[t];
}

__global__ __launch_bounds__(256) void k_scan_part_all(SP6 P) {
  SPTask tk = P.t[blockIdx.y];
  int b = blockIdx.x, t = threadIdx.x;
  int base = b * SCH;
  int s = 0;
  for (int i = t; i < SCH; i += 256) {
    int idx = base + i;
    if (idx < tk.n) s += tk.in[idx];
  }
  __shared__ int red[256];
  red[t] = s;
  __syncthreads();
  for (int d = 128; d > 0; d >>= 1) {
    if (t < d) red[t] += red[t + d];
    __syncthreads();
  }
  if (t == 0) tk.part[b] = red[0];
}

__global__ __launch_bounds__(256) void k_scan_down_all(SD6 P) {
  SDTask tk = P.t[blockIdx.y];
  int b = blockIdx.x, t = threadIdx.x;
  int lane = t & 63, wid = t >> 6;
  __shared__ int wsum[4];
  if (b == 0 && t == 0 && tk.total) {
    int s = 0;
    for (int w = 0; w < (int)gridDim.x; ++w) s += tk.part[w];
    *tk.total = s;
  }
  int offset = 0;
  for (int w = 0; w < b; ++w) offset += tk.part[w];
  int base = b * SCH;
  if (base >= tk.n) return;
  int idx0 = base + t * 16;
  int v[16];
  int s = 0;
#pragma unroll
  for (int i = 0; i < 16; ++i) {
    int idx = idx0 + i;
    v[i] = (idx < tk.n) ? tk.in[idx] : 0;
    s += v[i];
  }
  int inc = s;
  for (int d = 1; d < 64; d <<= 1) {
    int u = __shfl_up(inc, d, 64);
    if (lane >= d) inc += u;
  }
  if (lane == 63) wsum[wid] = inc;
  __syncthreads();
  int woff = 0;
  for (int w = 0; w < wid; ++w) woff += wsum[w];
  int ex = offset + woff + inc - s;
#pragma unroll
  for (int i = 0; i < 16; ++i) {
    int idx = idx0 + i;
    if (idx < tk.n) tk.out[idx] = ex;
    ex += v[i];
  }
}

__global__ __launch_bounds__(256) void k_scatter_all(Sc4 P) {
  ScTask tk = P.t[blockIdx.y];
  __shared__ int curA[256], curB[256];
  int blk = blockIdx.x, t = threadIdx.x;
  curA[t] = tk.base1[t * NBLK + blk];
  if (tk.mode == 0) curB[t] = tk.base2[t * NBLK + blk];
  __syncthreads();
  int per = (tk.n + NBLK - 1) / NBLK;
  int beg = blk * per, end = min(beg + per, tk.n);
  if (tk.mode == 0) {
    for (int i = beg + t; i < end; i += 256) {
      int s = tk.k1[i], d = tk.k2[i];
      int pa = atomicAdd(&curA[s >> tk.shift], 1);
      tk.o1[pa] = s;
      int pb = atomicAdd(&curB[d >> tk.shift], 1);
      tk.o2k[pb] = d;
      tk.o2v[pb] = s;
    }
  } else {
    for (int i = beg + t; i < end; i += 256) {
      int pa = atomicAdd(&curA[tk.k1[i] >> tk.shift], 1);
      tk.o1[pa] = i;
    }
  }
}

__global__ __launch_bounds__(256) void k_l2count_all(C4 P) {
  CTask tk = P.t[blockIdx.y];
  __shared__ int bins[512];
  int b = blockIdx.x, t = threadIdx.x;
  for (int f = t; f < tk.fine; f += 256) bins[f] = 0;
  __syncthreads();
  int beg = tk.base[b * NBLK];
  int end = (b == NBLK - 1) ? tk.n : tk.base[(b + 1) * NBLK];
  for (int i = beg + t; i < end; i += 256)
    atomicAdd(&bins[tk.tmpk[i] & (tk.fine - 1)], 1);
  __syncthreads();
  for (int f = t; f < tk.fine; f += 256)
    tk.deg[b * tk.fine + f] = bins[f];
}

__global__ __launch_bounds__(256) void k_norms_all(N2 P) {
  NTask tk = P.t[blockIdx.y];
  int i = blockIdx.x * blockDim.x + threadIdx.x;
  if (i < tk.n) {
    tk.ns[i] = rsqrtf(fmaxf((float)tk.outdeg[i], 1.f));
    tk.nd[i] = rsqrtf(fmaxf((float)tk.indeg[i], 1.f));
  }
}

__global__ __launch_bounds__(256) void k_l2scatter_all(L2T P) {
  LTask tk = P.t[blockIdx.y];
  __shared__ int cur[512];
  int b = blockIdx.x, t = threadIdx.x;
  int v0 = b << tk.shift;
  for (int f = t; f < tk.fine; f += 256) cur[f] = tk.rowptr[v0 + f];
  __syncthreads();
  int beg = tk.base[b * NBLK];
  int end = (b == NBLK - 1) ? tk.n : tk.base[(b + 1) * NBLK];
  for (int i = beg + t; i < end; i += 256) {
    int pos = atomicAdd(&cur[tk.tmpk[i] & (tk.fine - 1)], 1);
    tk.col[pos] = tk.tmpv[i];
  }
}

// ---------------- towers ------------------------------------------------------

// h[v,:] = fp16( ns[v] * (x[v,:] @ W) ); 64 nodes x 128 feats per 128-thread
// block, 8x8 per thread. x in LDS (broadcast reads), W streamed from global
// (L2-resident) -> 256 FMA per (8 global + 8 LDS) loads.
__global__ __launch_bounds__(128) void k_nl_gemm(GemP P) {
  __shared__ float xs[64][132];   // 33.8 KB
  int bx = blockIdx.x;
  GTask tk;
  int v0;
  if (bx < P.nb0) { tk = P.t[0]; v0 = bx * 64; }
  else            { tk = P.t[1]; v0 = (bx - P.nb0) * 64; }
  const int K = tk.K;
  int t = threadIdx.x;

  // stage x tile (coalesced scalar: 32 lanes over k, 4 rows per pass)
  {
    int m = t >> 5, k = t & 31;
    for (int kk = k; kk < K; kk += 32)
      for (int mm = m; mm < 64; mm += 4)
        xs[mm][kk] = tk.x[(size_t)(v0 + mm) * K + kk];
  }
  __syncthreads();

  int tn = (t >> 4) * 8;      // node base (0..56)
  int tf = (t & 15) * 8;      // feature base (0..120)

  float acc[8][8];
#pragma unroll
  for (int i = 0; i < 8; ++i)
#pragma unroll
    for (int j = 0; j < 8; ++j) acc[i][j] = 0.f;

  int k4max = K & ~3;
  for (int k4 = 0; k4 < k4max; k4 += 4) {
    float w[4][8];
#pragma unroll
    for (int q = 0; q < 4; ++q) {
      float4 w0 = *(const float4*)&tk.W[(size_t)(k4 + q) * D + tf];
      float4 w1 = *(const float4*)&tk.W[(size_t)(k4 + q) * D + tf + 4];
      w[q][0] = w0.x; w[q][1] = w0.y; w[q][2] = w0.z; w[q][3] = w0.w;
      w[q][4] = w1.x; w[q][5] = w1.y; w[q][6] = w1.z; w[q][7] = w1.w;
    }
#pragma unroll
    for (int i = 0; i < 8; ++i) {
      float4 a4 = *(const float4*)&xs[tn + i][k4];
      float av[4] = {a4.x, a4.y, a4.z, a4.w};
#pragma unroll
      for (int q = 0; q < 4; ++q)
#pragma unroll
        for (int j = 0; j < 8; ++j)
          acc[i][j] = fmaf(av[q], w[q][j], acc[i][j]);
    }
  }
  for (int k = k4max; k < K; ++k) {
    float4 w0 = *(const float4*)&tk.W[(size_t)k * D + tf];
    float4 w1 = *(const float4*)&tk.W[(size_t)k * D + tf + 4];
    float w[8] = {w0.x, w0.y, w0.z, w0.w, w1.x, w1.y, w1.z, w1.w};
#pragma unroll
    for (int i = 0; i < 8; ++i) {
      float av = xs[tn + i][k];
#pragma unroll
      for (int j = 0; j < 8; ++j) acc[i][j] = fmaf(av, w[j], acc[i][j]);
    }
  }

#pragma unroll
  for (int i = 0; i < 8; ++i) {
    int v = v0 + tn + i;
    float s = tk.ns[v];
    union { __half2 h2[4]; uint4 u; } pk;
#pragma unroll
    for (int q = 0; q < 4; ++q) {
      pk.h2[q].x = __float2half_rn(acc[i][2 * q] * s);
      pk.h2[q].y = __float2half_rn(acc[i][2 * q + 1] * s);
    }
    *(uint4*)&tk.h[(size_t)v * D + tf] = pk.u;
  }
}

// ---- aggregation: wave-per-node, 16 lanes x 8 feats (16B), 4 rows/instr -----
__global__ __launch_bounds__(256) void k_aggregate(AggP P) {
  int wid = threadIdx.x >> 6;
  int lane = threadIdx.x & 63;
  int gv = blockIdx.x * 4 + wid;
  if (gv >= P.ntot) return;
  ATask tk;
  int v;
  if (gv < P.np) { tk = P.t[0]; v = gv; }
  else           { tk = P.t[1]; v = gv - P.np; }
  int beg = tk.rowptr[v], end = tk.rowptr[v + 1];
  int f0 = (lane & 15) * 8;
  int rsel = lane >> 4;
  const __half* h = tk.h;
  const int* col = tk.col;

  float acc[8];
#pragma unroll
  for (int k = 0; k < 8; ++k) acc[k] = 0.f;

  for (int j = beg; j < end; j += 8) {
    int j0 = j + rsel, j1 = j + 4 + rsel;
    if (j0 < end) {
      int c0 = col[j0];
      uint4 r = *(const uint4*)&h[(size_t)c0 * D + f0];
      const __half2* q = (const __half2*)&r;
#pragma unroll
      for (int k = 0; k < 4; ++k) {
        float2 f = __half22float2(q[k]);
        acc[2 * k] += f.x; acc[2 * k + 1] += f.y;
      }
    }
    if (j1 < end) {
      int c1 = col[j1];
      uint4 r = *(const uint4*)&h[(size_t)c1 * D + f0];
      const __half2* q = (const __half2*)&r;
#pragma unroll
      for (int k = 0; k < 4; ++k) {
        float2 f = __half22float2(q[k]);
        acc[2 * k] += f.x; acc[2 * k + 1] += f.y;
      }
    }
  }

#pragma unroll
  for (int k = 0; k < 8; ++k) {
    acc[k] += __shfl_down(acc[k], 32, 64);
    acc[k] += __shfl_down(acc[k], 16, 64);
  }

  if (rsel == 0) {
    float s = tk.nd[v];
    float4 b0 = *(const float4*)&tk.b[f0];
    float4 b1 = *(const float4*)&tk.b[f0 + 4];
    float r[8];
    r[0] = fmaxf(fmaf(acc[0], s, b0.x), 0.f);
    r[1] = fmaxf(fmaf(acc[1], s, b0.y), 0.f);
    r[2] = fmaxf(fmaf(acc[2], s, b0.z), 0.f);
    r[3] = fmaxf(fmaf(acc[3], s, b0.w), 0.f);
    r[4] = fmaxf(fmaf(acc[4], s, b1.x), 0.f);
    r[5] = fmaxf(fmaf(acc[5], s, b1.y), 0.f);
    r[6] = fmaxf(fmaf(acc[6], s, b1.z), 0.f);
    r[7] = fmaxf(fmaf(acc[7], s, b1.w), 0.f);
    if (tk.halfOut) {
      union { __half2 h2[4]; uint4 u; } pk;
#pragma unroll
      for (int k = 0; k < 4; ++k) {
        pk.h2[k].x = __float2half_rn(r[2 * k]);
        pk.h2[k].y = __float2half_rn(r[2 * k + 1]);
      }
      *(uint4*)&((__half*)tk.out)[(size_t)v * D + f0] = pk.u;
    } else {
      float4 o0 = {r[0], r[1], r[2], r[3]};
      float4 o1 = {r[4], r[5], r[6], r[7]};
      *(float4*)&((float*)tk.out)[(size_t)v * D + f0] = o0;
      *(float4*)&((float*)tk.out)[(size_t)v * D + f0 + 4] = o1;
    }
  }
}

__device__ __forceinline__ void acc_half4(float4& a, const __half* p) {
  uint2 r = *(const uint2*)p;
  __half2 q0 = *(__half2*)&r.x;
  __half2 q1 = *(__half2*)&r.y;
  float2 f0 = __half22float2(q0);
  float2 f1 = __half22float2(q1);
  a.x += f0.x; a.y += f0.y; a.z += f1.x; a.w += f1.y;
}

__global__ __launch_bounds__(256) void k_seg_mean(M2 P) {
  MTask tk = P.t[blockIdx.y];
  int g = blockIdx.x, t = threadIdx.x;
  int slot = t >> 5;
  int c = (t & 31) * 4;
  int beg = tk.gbase[g * NBLK];
  int end = (g == (int)gridDim.x - 1) ? tk.n : tk.gbase[(g + 1) * NBLK];
  const __half* x = tk.x;
  const int* list = tk.list;

  float4 a0 = make_float4(0.f, 0.f, 0.f, 0.f);
  float4 a1 = make_float4(0.f, 0.f, 0.f, 0.f);
  int j = beg + slot;
  for (; j + 8 < end; j += 16) {
    int s0 = list[j], s1 = list[j + 8];
    acc_half4(a0, x + (size_t)s0 * D + c);
    acc_half4(a1, x + (size_t)s1 * D + c);
  }
  if (j < end)
    acc_half4(a0, x + (size_t)list[j] * D + c);
  a0.x += a1.x; a0.y += a1.y; a0.z += a1.z; a0.w += a1.w;

  a0.x += __shfl_down(a0.x, 32, 64);
  a0.y += __shfl_down(a0.y, 32, 64);
  a0.z += __shfl_down(a0.z, 32, 64);
  a0.w += __shfl_down(a0.w, 32, 64);

  __shared__ float sred[4][32 * 4];
  int wid = t >> 6, lane = t & 63;
  if (lane < 32) *(float4*)&sred[wid][lane * 4] = a0;
  __syncthreads();
  if (t < 32) {
    float4 s0 = *(const float4*)&sred[0][t * 4];
    float4 s1 = *(const float4*)&sred[1][t * 4];
    float4 s2 = *(const float4*)&sred[2][t * 4];
    float4 s3 = *(const float4*)&sred[3][t * 4];
    float inv = 1.f / fmaxf((float)(end - beg), 1.f);
    float4 r;
    r.x = (s0.x + s1.x + s2.x + s3.x) * inv;
    r.y = (s0.y + s1.y + s2.y + s3.y) * inv;
    r.z = (s0.z + s1.z + s2.z + s3.z) * inv;
    r.w = (s0.w + s1.w + s2.w + s3.w) * inv;
    *(float4*)&tk.out[(size_t)g * D + c] = r;
  }
}

__global__ void k_mlp(const float* __restrict__ cg, const float* __restrict__ pg,
                      const float* __restrict__ Wf1, const float* __restrict__ bf1,
                      const float* __restrict__ Wf2, const float* __restrict__ bf2,
                      float* __restrict__ out) {
  __shared__ float xs[256];
  __shared__ float red[128];
  int b = blockIdx.x, t = threadIdx.x;
  xs[t] = cg[b * D + t];
  xs[128 + t] = pg[b * D + t];
  __syncthreads();
  float acc = bf1[t];
  for (int k = 0; k < 256; ++k) acc = fmaf(xs[k], Wf1[k * D + t], acc);
  float hv = fmaxf(acc, 0.f);
  red[t] = hv * Wf2[t];
  for (int d = 64; d > 0; d >>= 1) {
    __syncthreads();
    if (t < d) red[t] += red[t + d];
  }
  if (t == 0) out[b] = red[0] + bf2[0];
}

// ---------------- launch ------------------------------------------------------

extern "C" void kernel_launch(void* const* d_in, const int* in_sizes, int n_in,
                              void* d_out, int out_size, void* d_ws, size_t ws_size,
                              hipStream_t stream) {
  const float* compound_feat = (const float*)d_in[0];
  const float* protein_feat  = (const float*)d_in[1];
  const int* c_src = (const int*)d_in[2];
  const int* c_dst = (const int*)d_in[3];
  const int* p_src = (const int*)d_in[4];
  const int* p_dst = (const int*)d_in[5];
  const int* c_gid = (const int*)d_in[6];
  const int* p_gid = (const int*)d_in[7];
  const float* Wc1 = (const float*)d_in[8];  const float* bc1 = (const float*)d_in[9];
  const float* Wc2 = (const float*)d_in[10]; const float* bc2 = (const float*)d_in[11];
  const float* Wp1 = (const float*)d_in[12]; const float* bp1 = (const float*)d_in[13];
  const float* Wp2 = (const float*)d_in[14]; const float* bp2 = (const float*)d_in[15];
  const float* Wf1 = (const float*)d_in[16]; const float* bf1 = (const float*)d_in[17];
  const float* Wf2 = (const float*)d_in[18]; const float* bf2 = (const float*)d_in[19];
  float* out = (float*)d_out;

  const int EC = in_sizes[2], EP = in_sizes[4];
  const int NC = in_sizes[6], NP = in_sizes[7];
  const int B  = out_size;
  const int KC = in_sizes[0] / NC;                 // 74
  const int cshift = __builtin_ctz(NC / 256), cfine = NC / 256;
  const int pshift = __builtin_ctz(NP / 256), pfine = NP / 256;
  const int HN = 256 * NBLK;

  char* ws = (char*)d_ws;
  size_t off = 0;
  auto alloc = [&](size_t bytes) -> void* {
    void* p = ws + off;
    off += (bytes + 255) & ~(size_t)255;
    return p;
  };

  int* H0 = (int*)alloc((size_t)HN * 4);
  int* H1 = (int*)alloc((size_t)HN * 4);
  int* H2 = (int*)alloc((size_t)HN * 4);
  int* H3 = (int*)alloc((size_t)HN * 4);
  int* H4 = (int*)alloc((size_t)HN * 4);
  int* H5 = (int*)alloc((size_t)HN * 4);
  int* partH = (int*)alloc((size_t)6 * 32 * 4);
  int* partD = (int*)alloc((size_t)2 * 32 * 4);
  int* tmps_c = (int*)alloc((size_t)EC * 4);
  int* tmpd_c = (int*)alloc((size_t)EC * 4);
  int* tmpv_c = (int*)alloc((size_t)EC * 4);
  int* tmps_p = (int*)alloc((size_t)EP * 4);
  int* tmpd_p = (int*)alloc((size_t)EP * 4);
  int* tmpv_p = (int*)alloc((size_t)EP * 4);
  int* c_outdeg = (int*)alloc((size_t)NC * 4);
  int* c_indeg  = (int*)alloc((size_t)NC * 4);
  int* p_outdeg = (int*)alloc((size_t)NP * 4);
  int* p_indeg  = (int*)alloc((size_t)NP * 4);
  float* c_ns = (float*)alloc((size_t)NC * 4);
  float* c_nd = (float*)alloc((size_t)NC * 4);
  float* p_ns = (float*)alloc((size_t)NP * 4);
  float* p_nd = (float*)alloc((size_t)NP * 4);
  int* c_rowptr = (int*)alloc((size_t)(NC + 1) * 4);
  int* p_rowptr = (int*)alloc((size_t)(NP + 1) * 4);
  int* c_col   = (int*)alloc((size_t)EC * 4);
  int* p_col   = (int*)alloc((size_t)EP * 4);
  int* cg_list = (int*)alloc((size_t)NC * 4);
  int* pg_list = (int*)alloc((size_t)NP * 4);
  __half* c_h  = (__half*)alloc((size_t)NC * D * 2);
  float*  c_m1 = (float*) alloc((size_t)NC * D * 4);
  __half* c_m2 = (__half*)alloc((size_t)NC * D * 2);
  __half* p_h  = (__half*)alloc((size_t)NP * D * 2);
  float*  p_m1 = (float*) alloc((size_t)NP * D * 4);
  __half* p_m2 = (__half*)alloc((size_t)NP * D * 2);
  float* cg = (float*)alloc((size_t)B * D * 4);
  float* pg = (float*)alloc((size_t)B * D * 4);
  (void)ws_size; (void)n_in;

  // 1) all six 256-bin histograms
  {
    H6 P = {{{c_src, EC, cshift, H0}, {c_dst, EC, cshift, H1}, {c_gid, NC, 0, H2},
             {p_src, EP, pshift, H3}, {p_dst, EP, pshift, H4}, {p_gid, NP, 0, H5}}};
    k_hist_all<<<dim3(NBLK, 6), 256, 0, stream>>>(P);
  }
  // 2) scan the six H arrays in place
  {
    SP6 Pp = {{{H0, HN, partH + 0}, {H1, HN, partH + 32}, {H2, HN, partH + 64},
               {H3, HN, partH + 96}, {H4, HN, partH + 128}, {H5, HN, partH + 160}}};
    k_scan_part_all<<<dim3(16, 6), 256, 0, stream>>>(Pp);
    SD6 Pd = {{{H0, HN, partH + 0, H0, nullptr}, {H1, HN, partH + 32, H1, nullptr},
               {H2, HN, partH + 64, H2, nullptr}, {H3, HN, partH + 96, H3, nullptr},
               {H4, HN, partH + 128, H4, nullptr}, {H5, HN, partH + 160, H5, nullptr}}};
    k_scan_down_all<<<dim3(16, 6), 256, 0, stream>>>(Pd);
  }
  // 3) all level-1 scatters
  {
    Sc4 P = {{{c_src, c_dst, EC, cshift, H0, H1, tmps_c, tmpd_c, tmpv_c, 0},
              {p_src, p_dst, EP, pshift, H3, H4, tmps_p, tmpd_p, tmpv_p, 0},
              {c_gid, nullptr, NC, 0, H2, nullptr, cg_list, nullptr, nullptr, 1},
              {p_gid, nullptr, NP, 0, H5, nullptr, pg_list, nullptr, nullptr, 1}}};
    k_scatter_all<<<dim3(NBLK, 4), 256, 0, stream>>>(P);
  }
  // 4) level-2 counts -> degrees
  {
    C4 P = {{{tmps_c, H0, EC, cfine, c_outdeg}, {tmpd_c, H1, EC, cfine, c_indeg},
             {tmps_p, H3, EP, pfine, p_outdeg}, {tmpd_p, H4, EP, pfine, p_indeg}}};
    k_l2count_all<<<dim3(NBLK, 4), 256, 0, stream>>>(P);
  }
  // 5) scan indegrees -> rowptr
  {
    SP6 Pp; Pp.t[0] = {c_indeg, NC, partD + 0}; Pp.t[1] = {p_indeg, NP, partD + 32};
    Pp.t[2] = Pp.t[3] = Pp.t[4] = Pp.t[5] = SPTask{c_indeg, 0, partD + 0};
    k_scan_part_all<<<dim3(32, 2), 256, 0, stream>>>(Pp);
    SD6 Pd; Pd.t[0] = {c_indeg, NC, partD + 0, c_rowptr, c_rowptr + NC};
    Pd.t[1] = {p_indeg, NP, partD + 32, p_rowptr, p_rowptr + NP};
    Pd.t[2] = Pd.t[3] = Pd.t[4] = Pd.t[5] = Pd.t[0];
    k_scan_down_all<<<dim3(32, 2), 256, 0, stream>>>(Pd);
  }
  // 6) norms
  {
    N2 P = {{{c_outdeg, c_indeg, c_ns, c_nd, NC}, {p_outdeg, p_indeg, p_ns, p_nd, NP}}};
    k_norms_all<<<dim3((NP + 255) / 256, 2), 256, 0, stream>>>(P);
  }
  // 7) level-2 scatter -> CSR col
  {
    L2T P = {{{tmpd_c, tmpv_c, H1, EC, c_rowptr, cshift, cfine, c_col},
              {tmpd_p, tmpv_p, H4, EP, p_rowptr, pshift, pfine, p_col}}};
    k_l2scatter_all<<<dim3(NBLK, 2), 256, 0, stream>>>(P);
  }

  // ---- towers (flattened grids: protein first) ----
  const int gnb = NP / 64 + NC / 64;
  const int anb = (NP + NC + 3) / 4;
  {
    GemP P = {{{protein_feat, p_ns, Wp1, p_h, D}, {compound_feat, c_ns, Wc1, c_h, KC}}, NP / 64};
    k_nl_gemm<<<gnb, 128, 0, stream>>>(P);
  }
  {
    AggP P = {{{p_h, p_rowptr, p_col, p_nd, bp1, p_m1, 0},
               {c_h, c_rowptr, c_col, c_nd, bc1, c_m1, 0}}, NP, NP + NC};
    k_aggregate<<<anb, 256, 0, stream>>>(P);
  }
  {
    GemP P = {{{p_m1, p_ns, Wp2, p_h, D}, {c_m1, c_ns, Wc2, c_h, D}}, NP / 64};
    k_nl_gemm<<<gnb, 128, 0, stream>>>(P);
  }
  {
    AggP P = {{{p_h, p_rowptr, p_col, p_nd, bp2, p_m2, 1},
               {c_h, c_rowptr, c_col, c_nd, bc2, c_m2, 1}}, NP, NP + NC};
    k_aggregate<<<anb, 256, 0, stream>>>(P);
  }
  {
    M2 P = {{{c_m2, H2, NC, cg_list, cg}, {p_m2, H5, NP, pg_list, pg}}};
    k_seg_mean<<<dim3(B, 2), 256, 0, stream>>>(P);
  }

  k_mlp<<<B, D, 0, stream>>>(cg, pg, Wf1, bf1, Wf2, bf2, out);
}